// Round 10
// baseline (2031.650 us; speedup 1.0000x reference)
//
#include <hip/hip_runtime.h>
#include <math.h>

#define N_NODES 50000
#define N_EDGES 600000
#define IN_DIM 64
#define DMODEL 128
#define N_LAYERS 8
#define N_ETYPES 44
#define N_MENTIONS 100000
#define N_VARS 20000
#define OUT_DIM 100

#define EPI_BIAS 0
#define EPI_BIAS_RELU 1
#define EPI_DEG_GELU 2
#define EPI_NONE 3

#define SCL  6.103515625e-05f   /* 2^-14: pre-scale into f16 range (|h| can reach ~1e7) */
#define SCLI 16384.0f

typedef _Float16 f16x8 __attribute__((ext_vector_type(8)));
typedef _Float16 f16x4 __attribute__((ext_vector_type(4)));
typedef float f32x4 __attribute__((ext_vector_type(4)));

__device__ __forceinline__ float gelu_exact(float x) {
    return 0.5f * x * (1.0f + erff(x * 0.70710678118654752f));
}

// ---------------- weight prep: transpose [K,N]->[Npad,K] and split fp32 -> f16 hi+lo ----------
__global__ void wprep(const float* __restrict__ src, _Float16* __restrict__ dhi,
                      _Float16* __restrict__ dlo, int K, int Nsrc, int Npad,
                      long srcLS, long dstLS, int cat) {
    __shared__ float sh[16][17];
    int z = blockIdx.z;
    src += (size_t)z * srcLS;
    dhi += (size_t)z * dstLS;
    dlo += (size_t)z * dstLS;
    int n0 = blockIdx.x * 16, k0 = blockIdx.y * 16;
    int tx = threadIdx.x, ty = threadIdx.y;
    int nr = n0 + tx, kr = k0 + ty;
    float v;
    if (cat) {
        int half = nr >> 8;
        int nc = nr & 255;
        v = src[(size_t)(kr + half * 128) * 256 + nc];
    } else {
        v = (nr < Nsrc) ? src[(size_t)kr * Nsrc + nr] : 0.f;
    }
    sh[ty][tx] = v;
    __syncthreads();
    float x = sh[tx][ty];
    int n = n0 + ty, k = k0 + tx;
    _Float16 hi = (_Float16)x;
    float lo = x - (float)hi;
    dhi[(size_t)n * K + k] = hi;
    dlo[(size_t)n * K + k] = (_Float16)lo;
}

// ---------------- 3xF16 MFMA GEMM, 64x64 tile, LDS-staged (ASPLIT=0 paths) ----------------
// MSWZ=1: XCD-aware grid remap for A-panel L2 reuse (R3: -117us; R5: generalized NX).
// R4 lesson: fusing the BW-pinned gather with MFMA dropped gather occupancy 68%->18%.
// R7+R8 lessons: 128^2 and 64x128 tiles both regressed -> short-K shapes want occupancy.
template<int EPI, int ASPLIT, int OSPLIT, int MSWZ = 0, int NX = 8>
__global__ __launch_bounds__(256) void gemm3h(
        const float* __restrict__ A, const _Float16* __restrict__ Ahi,
        const _Float16* __restrict__ Alo,
        const _Float16* __restrict__ Bh, const _Float16* __restrict__ Bl,
        const float* __restrict__ bias, const int* __restrict__ deg,
        float* __restrict__ C, _Float16* __restrict__ Chi, _Float16* __restrict__ Clo,
        int M, int N, int K, int ldC) {
    __shared__ _Float16 Ah[64 * 56], Al[64 * 56], Bsh[64 * 56], Bsl[64 * 56];
    int t = threadIdx.x;
    int m0, n0;
    if (MSWZ) {
        int mpanels = (M + 63) >> 6;
        int per = (mpanels + 7) >> 3;                     // m-panels per XCD
        int mi = blockIdx.x * per + blockIdx.y / NX;
        if (mi >= mpanels) return;                        // uniform early-out, pre-barrier
        m0 = mi * 64;
        n0 = (blockIdx.y % NX) * 64;
    } else {
        m0 = blockIdx.y * 64;
        n0 = blockIdx.x * 64;
    }
    int ar = t >> 2, ac = (t & 3) * 8;
    int btt = t & 127, br = btt >> 1, bc = (btt & 1) * 16;
    const _Float16* Bsrc = (t < 128) ? Bh : Bl;
    _Float16* Bdst = (t < 128) ? Bsh : Bsl;
    int lane = t & 63, wid = t >> 6;
    int wm = (wid >> 1) * 32, wn = (wid & 1) * 32;
    int quad = lane >> 4, l15 = lane & 15;
    f32x4 acc[2][2] = {};
    bool arow_ok = (m0 + ar) < M;
    const float* Aptr = ASPLIT ? nullptr : (A + (size_t)(m0 + ar) * K + ac);
    const _Float16* Ahp = ASPLIT ? (Ahi + (size_t)(m0 + ar) * K + ac) : nullptr;
    const _Float16* Alp = ASPLIT ? (Alo + (size_t)(m0 + ar) * K + ac) : nullptr;
    const _Float16* Bptr = Bsrc + (size_t)(n0 + br) * K + bc;

    for (int k0 = 0; k0 < K; k0 += 32) {
        f16x8 hv = {}, lv = {};
        if (ASPLIT) {
            if (arow_ok) {
                hv = *(const f16x8*)(Ahp + k0);
                lv = *(const f16x8*)(Alp + k0);
            }
        } else {
            float4 v0 = {0, 0, 0, 0}, v1 = {0, 0, 0, 0};
            if (arow_ok) {
                v0 = *(const float4*)(Aptr + k0);
                v1 = *(const float4*)(Aptr + k0 + 4);
            }
            float xs[8] = {v0.x, v0.y, v0.z, v0.w, v1.x, v1.y, v1.z, v1.w};
#pragma unroll
            for (int j = 0; j < 8; j++) {
                float s = xs[j] * SCL;
                _Float16 h = (_Float16)s;
                hv[j] = h;
                lv[j] = (_Float16)(s - (float)h);
            }
        }
        *(f16x8*)&Ah[ar * 56 + ac] = hv;
        *(f16x8*)&Al[ar * 56 + ac] = lv;
        f16x8 b0 = *(const f16x8*)(Bptr + k0);
        f16x8 b1v = *(const f16x8*)(Bptr + k0 + 8);
        *(f16x8*)&Bdst[br * 56 + bc] = b0;
        *(f16x8*)&Bdst[br * 56 + bc + 8] = b1v;
        __syncthreads();

        f16x8 afh[2], afl[2], bfh[2], bfl[2];
#pragma unroll
        for (int i = 0; i < 2; i++) {
            int am = (wm + i * 16 + l15) * 56 + quad * 8;
            afh[i] = *(const f16x8*)&Ah[am];
            afl[i] = *(const f16x8*)&Al[am];
            int bn = (wn + i * 16 + l15) * 56 + quad * 8;
            bfh[i] = *(const f16x8*)&Bsh[bn];
            bfl[i] = *(const f16x8*)&Bsl[bn];
        }
#pragma unroll
        for (int i = 0; i < 2; i++)
#pragma unroll
            for (int j = 0; j < 2; j++) {
                acc[i][j] = __builtin_amdgcn_mfma_f32_16x16x32_f16(afh[i], bfh[j], acc[i][j], 0, 0, 0);
                acc[i][j] = __builtin_amdgcn_mfma_f32_16x16x32_f16(afh[i], bfl[j], acc[i][j], 0, 0, 0);
                acc[i][j] = __builtin_amdgcn_mfma_f32_16x16x32_f16(afl[i], bfh[j], acc[i][j], 0, 0, 0);
            }
        __syncthreads();
    }

#pragma unroll
    for (int i = 0; i < 2; i++) {
        int rowb = m0 + wm + i * 16 + quad * 4;
#pragma unroll
        for (int j = 0; j < 2; j++) {
            int col = n0 + wn + j * 16 + l15;
            if (col >= N) continue;
#pragma unroll
            for (int r = 0; r < 4; r++) {
                int row = rowb + r;
                if (row >= M) continue;
                float v = acc[i][j][r] * SCLI;
                if (EPI == EPI_BIAS) { v += bias[col]; }
                else if (EPI == EPI_BIAS_RELU) { v += bias[col]; v = fmaxf(v, 0.f); }
                else if (EPI == EPI_DEG_GELU) { v += (float)deg[row] * bias[col]; v = gelu_exact(v); }
                if (OSPLIT == 0) {
                    C[(size_t)row * ldC + col] = v;
                } else if (OSPLIT == 1) {
                    float s = v * SCL;
                    _Float16 h = (_Float16)s;
                    size_t idx = (size_t)row * ldC + col;
                    Chi[idx] = h;
                    Clo[idx] = (_Float16)(s - (float)h);
                } else if (OSPLIT == 3) {
                    if (col < 256) C[(size_t)row * 256 + col] = v;
                    else Chi[(size_t)row * 256 + (col - 256)] = (_Float16)(v * SCL);
                }
            }
        }
    }
}

// ---------------- 3xF16 MFMA GEMM, 64x64 tile, LDS-FREE register path (R10) ----------------
// gemm3h is VALU/barrier-bound: per K-step per thread = 4 staged loads + 4 LDS writes +
// 8 ds_reads + 2 barriers for 12 MFMA (m80-style: ~17% MFMA util). R7/R8 showed bigger
// tiles lose occupancy. R10: load MFMA fragments DIRECTLY from global (A=hhi/hlo and
// B=weights are both f16 arrays; B is 256KB L2-hot, A-panels L2-hot via MSWZ). Fragment
// pattern (16 rows x 16B at quad offsets) fully consumes each 64B line with 4 lanes ->
// well-coalesced. Per K-step per thread: 8 global 16B loads + 12 MFMA, ZERO LDS, ZERO
// barriers -> pure TLP latency hiding (the regime edge_agg proves works at 3.5 TB/s).
// Numerics: identical MFMA sequence as gemm3h -> bit-identical output. ASPLIT-only.
template<int EPI, int OSPLIT, int MSWZ, int NX>
__global__ __launch_bounds__(256) void gemm3r(
        const _Float16* __restrict__ Ahi, const _Float16* __restrict__ Alo,
        const _Float16* __restrict__ Bh, const _Float16* __restrict__ Bl,
        const float* __restrict__ bias, const int* __restrict__ deg,
        float* __restrict__ C, _Float16* __restrict__ Chi, _Float16* __restrict__ Clo,
        int M, int N, int K, int ldC) {
    int t = threadIdx.x;
    int m0, n0;
    if (MSWZ) {
        int mpanels = (M + 63) >> 6;
        int per = (mpanels + 7) >> 3;
        int mi = blockIdx.x * per + blockIdx.y / NX;
        if (mi >= mpanels) return;
        m0 = mi * 64;
        n0 = (blockIdx.y % NX) * 64;
    } else {
        m0 = blockIdx.y * 64;
        n0 = blockIdx.x * 64;
    }
    int lane = t & 63, wid = t >> 6;
    int wm = (wid >> 1) * 32, wn = (wid & 1) * 32;
    int quad = lane >> 4, l15 = lane & 15;
    f32x4 acc[2][2] = {};
    // A rows for fragments i=0,1 (clamped: dup row feeds dead acc; stores row-guarded)
    int ar0 = m0 + wm + l15;
    int ar1 = ar0 + 16;
    if (ar0 > M - 1) ar0 = M - 1;
    if (ar1 > M - 1) ar1 = M - 1;
    const _Float16* a0h = Ahi + (size_t)ar0 * K + quad * 8;
    const _Float16* a0l = Alo + (size_t)ar0 * K + quad * 8;
    const _Float16* a1h = Ahi + (size_t)ar1 * K + quad * 8;
    const _Float16* a1l = Alo + (size_t)ar1 * K + quad * 8;
    // B rows (wprep pads B to Npad >= n0+wn+16+15, always valid)
    int bn0 = n0 + wn + l15;
    int bn1 = bn0 + 16;
    const _Float16* b0h = Bh + (size_t)bn0 * K + quad * 8;
    const _Float16* b0l = Bl + (size_t)bn0 * K + quad * 8;
    const _Float16* b1h = Bh + (size_t)bn1 * K + quad * 8;
    const _Float16* b1l = Bl + (size_t)bn1 * K + quad * 8;

    for (int k0 = 0; k0 < K; k0 += 32) {
        f16x8 afh[2], afl[2], bfh[2], bfl[2];
        afh[0] = *(const f16x8*)(a0h + k0);
        afl[0] = *(const f16x8*)(a0l + k0);
        afh[1] = *(const f16x8*)(a1h + k0);
        afl[1] = *(const f16x8*)(a1l + k0);
        bfh[0] = *(const f16x8*)(b0h + k0);
        bfl[0] = *(const f16x8*)(b0l + k0);
        bfh[1] = *(const f16x8*)(b1h + k0);
        bfl[1] = *(const f16x8*)(b1l + k0);
#pragma unroll
        for (int i = 0; i < 2; i++)
#pragma unroll
            for (int j = 0; j < 2; j++) {
                acc[i][j] = __builtin_amdgcn_mfma_f32_16x16x32_f16(afh[i], bfh[j], acc[i][j], 0, 0, 0);
                acc[i][j] = __builtin_amdgcn_mfma_f32_16x16x32_f16(afh[i], bfl[j], acc[i][j], 0, 0, 0);
                acc[i][j] = __builtin_amdgcn_mfma_f32_16x16x32_f16(afl[i], bfh[j], acc[i][j], 0, 0, 0);
            }
    }

#pragma unroll
    for (int i = 0; i < 2; i++) {
        int rowb = m0 + wm + i * 16 + quad * 4;
#pragma unroll
        for (int j = 0; j < 2; j++) {
            int col = n0 + wn + j * 16 + l15;
            if (col >= N) continue;
#pragma unroll
            for (int r = 0; r < 4; r++) {
                int row = rowb + r;
                if (row >= M) continue;
                float v = acc[i][j][r] * SCLI;
                if (EPI == EPI_BIAS) { v += bias[col]; }
                else if (EPI == EPI_BIAS_RELU) { v += bias[col]; v = fmaxf(v, 0.f); }
                else if (EPI == EPI_DEG_GELU) { v += (float)deg[row] * bias[col]; v = gelu_exact(v); }
                if (OSPLIT == 0) {
                    C[(size_t)row * ldC + col] = v;
                } else if (OSPLIT == 1) {
                    float s = v * SCL;
                    _Float16 h = (_Float16)s;
                    size_t idx = (size_t)row * ldC + col;
                    Chi[idx] = h;
                    Clo[idx] = (_Float16)(s - (float)h);
                } else if (OSPLIT == 3) {
                    // mixed W1 output: Hd fp32 / Hs single f16 (SCL-scaled)
                    if (col < 256) C[(size_t)row * 256 + col] = v;
                    else Chi[(size_t)row * 256 + (col - 256)] = (_Float16)(v * SCL);
                }
            }
        }
    }
}

// ---------------- CSR build ----------------
__global__ void count_deg(const int* __restrict__ dst, int* __restrict__ deg) {
    int e = blockIdx.x * blockDim.x + threadIdx.x;
    if (e < N_EDGES) atomicAdd(&deg[dst[e]], 1);
}

#define SCAN_B 1024
#define SCAN_NB ((N_NODES + SCAN_B - 1) / SCAN_B)

__global__ void scan_local(const int* __restrict__ deg, int* __restrict__ offs,
                           int* __restrict__ bsum, int n) {
    __shared__ int sh[SCAN_B];
    int t = threadIdx.x;
    int i = blockIdx.x * SCAN_B + t;
    int v = (i < n) ? deg[i] : 0;
    sh[t] = v;
    __syncthreads();
    for (int o = 1; o < SCAN_B; o <<= 1) {
        int u = (t >= o) ? sh[t - o] : 0;
        __syncthreads();
        sh[t] += u;
        __syncthreads();
    }
    if (i < n) offs[i] = sh[t] - v;
    if (t == SCAN_B - 1) bsum[blockIdx.x] = sh[t];
}

__global__ void scan_block(int* __restrict__ bsum, int nb) {
    __shared__ int sh[64];
    int t = threadIdx.x;
    int v = (t < nb) ? bsum[t] : 0;
    sh[t] = v;
    __syncthreads();
    for (int o = 1; o < 64; o <<= 1) {
        int u = (t >= o) ? sh[t - o] : 0;
        __syncthreads();
        sh[t] += u;
        __syncthreads();
    }
    if (t < nb) bsum[t] = sh[t] - v;
}

__global__ void scan_final(int* __restrict__ offs, const int* __restrict__ bsum,
                           int* __restrict__ cursor, int n, int total) {
    int i = blockIdx.x * SCAN_B + threadIdx.x;
    if (i < n) {
        int o = offs[i] + bsum[blockIdx.x];
        offs[i] = o;
        cursor[i] = o;
    }
    if (i == n) offs[n] = total;
}

__global__ void place_edges(const int* __restrict__ src, const int* __restrict__ dst,
                            const int* __restrict__ lab, int* __restrict__ cursor,
                            int* __restrict__ src_s, int* __restrict__ lab_s) {
    int e = blockIdx.x * blockDim.x + threadIdx.x;
    if (e < N_EDGES) {
        int pos = atomicAdd(&cursor[dst[e]], 1);
        src_s[pos] = src[e];
        lab_s[pos] = lab[e];
    }
}

// ---------------- per-etype projection, all layers in one dispatch ----------------
// Stores etp pre-scaled by SCL (R6): edge_agg's relu-sum runs in the scaled domain.
__global__ void etype_proj_all(const float* __restrict__ edge_emb, const float* __restrict__ mlp_W1,
                               const float* __restrict__ mlp_b1, float* __restrict__ etp_all) {
    int et = blockIdx.x;   // 0..43
    int l  = blockIdx.y;   // 0..7
    int c = threadIdx.x;   // 256
    const float* ee = edge_emb + (size_t)l * N_ETYPES * DMODEL + (size_t)et * DMODEL;
    const float* W  = mlp_W1 + (size_t)l * 384 * 256 + (size_t)256 * 256;
    float s = mlp_b1[(size_t)l * 256 + c];
    for (int k = 0; k < DMODEL; k++)
        s += ee[k] * W[(size_t)k * 256 + c];
    etp_all[((size_t)l * N_ETYPES + et) * 256 + c] = s * SCL;
}

// ---------------- edge aggregation: wave-per-node, 2-deep software pipeline (R9) ----------------
// R6: Hs gathered as single f16 (512B/row); Hd fp32 (coherent-error side); SCL-scaled domain.
// R9: 2-deep prefetch pipeline (+1.5us only — compiler already scheduled well; kept, free).
// R2/R4: BW-pinned above ~68% occupancy; keep lean. launch_bounds(256,8) pins VGPR <= 64.
__global__ __launch_bounds__(256, 8) void edge_agg(
        const float* __restrict__ HHd, const _Float16* __restrict__ HHs,
        const float* __restrict__ etp,
        const int* __restrict__ offsets, const int* __restrict__ src_s,
        const int* __restrict__ lab_s, _Float16* __restrict__ Phi,
        _Float16* __restrict__ Plo) {
    int wid = threadIdx.x >> 6, tl = threadIdx.x & 63;
    int i = blockIdx.x * 4 + wid;
    if (i >= N_NODES) return;
    int c4 = tl * 4;
    float4 hd = *(const float4*)&HHd[(size_t)i * 256 + c4];
    float hdx = hd.x * SCL, hdy = hd.y * SCL, hdz = hd.z * SCL, hdw = hd.w * SCL;
    float4 acc = {0.f, 0.f, 0.f, 0.f};
    int e0 = offsets[i], e1 = offsets[i + 1];
    int e = e0;
    int ng = (e1 - e0) >> 2;
    if (ng > 0) {
        int s0 = src_s[e0],     s1 = src_s[e0 + 1], s2 = src_s[e0 + 2], s3 = src_s[e0 + 3];
        int l0 = lab_s[e0],     l1 = lab_s[e0 + 1], l2 = lab_s[e0 + 2], l3 = lab_s[e0 + 3];
        f16x4 hs0 = *(const f16x4*)&HHs[(size_t)s0 * 256 + c4];
        f16x4 hs1 = *(const f16x4*)&HHs[(size_t)s1 * 256 + c4];
        f16x4 hs2 = *(const f16x4*)&HHs[(size_t)s2 * 256 + c4];
        f16x4 hs3 = *(const f16x4*)&HHs[(size_t)s3 * 256 + c4];
        for (int g = 0; g < ng; ++g) {
            int en = e0 + g * 4 + 4;
            if (en > e1 - 4) en = e1 - 4;
            int t0 = src_s[en],     t1 = src_s[en + 1], t2 = src_s[en + 2], t3 = src_s[en + 3];
            int m0 = lab_s[en],     m1 = lab_s[en + 1], m2 = lab_s[en + 2], m3 = lab_s[en + 3];
            f16x4 nh0 = *(const f16x4*)&HHs[(size_t)t0 * 256 + c4];
            f16x4 nh1 = *(const f16x4*)&HHs[(size_t)t1 * 256 + c4];
            f16x4 nh2 = *(const f16x4*)&HHs[(size_t)t2 * 256 + c4];
            f16x4 nh3 = *(const f16x4*)&HHs[(size_t)t3 * 256 + c4];
            float4 et0 = *(const float4*)&etp[l0 * 256 + c4];
            float4 et1 = *(const float4*)&etp[l1 * 256 + c4];
            float4 et2 = *(const float4*)&etp[l2 * 256 + c4];
            float4 et3 = *(const float4*)&etp[l3 * 256 + c4];
            acc.x += fmaxf(hdx + (float)hs0[0] + et0.x, 0.f) + fmaxf(hdx + (float)hs1[0] + et1.x, 0.f)
                   + fmaxf(hdx + (float)hs2[0] + et2.x, 0.f) + fmaxf(hdx + (float)hs3[0] + et3.x, 0.f);
            acc.y += fmaxf(hdy + (float)hs0[1] + et0.y, 0.f) + fmaxf(hdy + (float)hs1[1] + et1.y, 0.f)
                   + fmaxf(hdy + (float)hs2[1] + et2.y, 0.f) + fmaxf(hdy + (float)hs3[1] + et3.y, 0.f);
            acc.z += fmaxf(hdz + (float)hs0[2] + et0.z, 0.f) + fmaxf(hdz + (float)hs1[2] + et1.z, 0.f)
                   + fmaxf(hdz + (float)hs2[2] + et2.z, 0.f) + fmaxf(hdz + (float)hs3[2] + et3.z, 0.f);
            acc.w += fmaxf(hdw + (float)hs0[3] + et0.w, 0.f) + fmaxf(hdw + (float)hs1[3] + et1.w, 0.f)
                   + fmaxf(hdw + (float)hs2[3] + et2.w, 0.f) + fmaxf(hdw + (float)hs3[3] + et3.w, 0.f);
            hs0 = nh0; hs1 = nh1; hs2 = nh2; hs3 = nh3;
            l0 = m0; l1 = m1; l2 = m2; l3 = m3;
        }
        e = e0 + ng * 4;
    }
    for (; e < e1; ++e) {
        int s0 = src_s[e], l0 = lab_s[e];
        f16x4 hs0 = *(const f16x4*)&HHs[(size_t)s0 * 256 + c4];
        float4 et0 = *(const float4*)&etp[l0 * 256 + c4];
        acc.x += fmaxf(hdx + (float)hs0[0] + et0.x, 0.f);
        acc.y += fmaxf(hdy + (float)hs0[1] + et0.y, 0.f);
        acc.z += fmaxf(hdz + (float)hs0[2] + et0.z, 0.f);
        acc.w += fmaxf(hdw + (float)hs0[3] + et0.w, 0.f);
    }
    float sv[4] = {acc.x, acc.y, acc.z, acc.w};
    f16x4 ph, pl;
#pragma unroll
    for (int j = 0; j < 4; j++) {
        _Float16 h = (_Float16)sv[j];
        ph[j] = h;
        pl[j] = (_Float16)(sv[j] - (float)h);
    }
    *(f16x4*)&Phi[(size_t)i * 256 + c4] = ph;
    *(f16x4*)&Plo[(size_t)i * 256 + c4] = pl;
}

// ---------------- readout ----------------
__global__ void readout_scatter(const _Float16* __restrict__ hhi, const _Float16* __restrict__ hlo,
                                const int* __restrict__ vg, const int* __restrict__ vs,
                                float* __restrict__ sums, int* __restrict__ cnt) {
    int m = blockIdx.x * 2 + (threadIdx.x >> 7);
    int c = threadIdx.x & 127;
    if (m >= N_MENTIONS) return;
    int node = vg[m];
    int v = vs[m];
    size_t idx = (size_t)node * DMODEL + c;
    float x = ((float)hhi[idx] + (float)hlo[idx]) * SCLI;
    atomicAdd(&sums[(size_t)v * DMODEL + c], x);
    if (c == 0) atomicAdd(&cnt[v], 1);
}

__global__ void divide_kernel(float* __restrict__ sums, const int* __restrict__ cnt) {
    int v = blockIdx.x;
    int c = threadIdx.x;  // 128
    float d = (float)max(cnt[v], 1);
    sums[(size_t)v * DMODEL + c] /= d;
}

// ---------------- launcher ----------------
extern "C" void kernel_launch(void* const* d_in, const int* in_sizes, int n_in,
                              void* d_out, int out_size, void* d_ws, size_t ws_size,
                              hipStream_t stream) {
    const float* node_labels = (const float*)d_in[0];
    const int*   edges       = (const int*)d_in[1];
    const int*   edge_labels = (const int*)d_in[2];
    const int*   var_gather  = (const int*)d_in[3];
    const int*   var_scatter = (const int*)d_in[4];
    const float* enc_W0 = (const float*)d_in[7];
    const float* enc_b0 = (const float*)d_in[8];
    const float* enc_W1 = (const float*)d_in[9];
    const float* enc_b1 = (const float*)d_in[10];
    const float* edge_emb = (const float*)d_in[11];
    const float* mlp_W1 = (const float*)d_in[12];
    const float* mlp_b1 = (const float*)d_in[13];
    const float* mlp_W2 = (const float*)d_in[14];
    const float* mlp_b2 = (const float*)d_in[15];
    const float* dec_W0 = (const float*)d_in[16];
    const float* dec_b0 = (const float*)d_in[17];
    const float* dec_Wl = (const float*)d_in[18];
    const float* dec_bl = (const float*)d_in[19];
    float* out = (float*)d_out;

    char* ws = (char*)d_ws;
    size_t off = 0;
    auto alloc = [&](size_t bytes) -> void* {
        void* p = ws + off;
        off += (bytes + 255) & ~(size_t)255;
        return p;
    };
    float*    HHd   = (float*)alloc((size_t)N_NODES * 256 * 4);       // 51.2 MB (Hd, fp32)
    _Float16* HHs   = (_Float16*)alloc((size_t)N_NODES * 256 * 2);    // 25.6 MB (Hs, f16)
    _Float16* hhi   = (_Float16*)alloc((size_t)N_NODES * DMODEL * 2);
    _Float16* hlo   = (_Float16*)alloc((size_t)N_NODES * DMODEL * 2);
    _Float16* Phi   = (_Float16*)alloc((size_t)N_NODES * 256 * 2);
    _Float16* Plo   = (_Float16*)alloc((size_t)N_NODES * 256 * 2);
    float* etp_all = (float*)alloc((size_t)N_LAYERS * N_ETYPES * 256 * 4);
    int* deg    = (int*)alloc((size_t)N_NODES * 4);
    int* offs   = (int*)alloc((size_t)(N_NODES + 1) * 4);
    int* cursor = (int*)alloc((size_t)N_NODES * 4);
    int* bsum   = (int*)alloc(64 * 4);
    int* src_s  = (int*)alloc((size_t)N_EDGES * 4);
    int* lab_s  = (int*)alloc((size_t)N_EDGES * 4);
    _Float16* W1t_h = (_Float16*)alloc((size_t)N_LAYERS * 512 * 128 * 2);
    _Float16* W1t_l = (_Float16*)alloc((size_t)N_LAYERS * 512 * 128 * 2);
    _Float16* W2t_h = (_Float16*)alloc((size_t)N_LAYERS * 128 * 256 * 2);
    _Float16* W2t_l = (_Float16*)alloc((size_t)N_LAYERS * 128 * 256 * 2);
    _Float16* e0h = (_Float16*)alloc(128 * 64 * 2);
    _Float16* e0l = (_Float16*)alloc(128 * 64 * 2);
    _Float16* e1h = (_Float16*)alloc(128 * 128 * 2);
    _Float16* e1l = (_Float16*)alloc(128 * 128 * 2);
    _Float16* d0h = (_Float16*)alloc(128 * 128 * 2);
    _Float16* d0l = (_Float16*)alloc(128 * 128 * 2);
    _Float16* dlh = (_Float16*)alloc(128 * 128 * 2);
    _Float16* dll = (_Float16*)alloc(128 * 128 * 2);
    _Float16* hench = (_Float16*)alloc((size_t)N_NODES * DMODEL * 2);
    _Float16* hencl = (_Float16*)alloc((size_t)N_NODES * DMODEL * 2);
    float* vsum = (float*)alloc((size_t)N_VARS * DMODEL * 4);
    int*   vcnt = (int*)alloc((size_t)N_VARS * 4);
    _Float16* dtmph = (_Float16*)alloc((size_t)N_VARS * DMODEL * 2);
    _Float16* dtmpl = (_Float16*)alloc((size_t)N_VARS * DMODEL * 2);

    const int* e_src = edges;
    const int* e_dst = edges + N_EDGES;

    hipMemsetAsync(deg, 0, (size_t)N_NODES * 4, stream);
    hipMemsetAsync(vsum, 0, (size_t)N_VARS * DMODEL * 4, stream);
    hipMemsetAsync(vcnt, 0, (size_t)N_VARS * 4, stream);

    // CSR build (hierarchical scan)
    count_deg<<<(N_EDGES + 255) / 256, 256, 0, stream>>>(e_dst, deg);
    scan_local<<<SCAN_NB, SCAN_B, 0, stream>>>(deg, offs, bsum, N_NODES);
    scan_block<<<1, 64, 0, stream>>>(bsum, SCAN_NB);
    scan_final<<<SCAN_NB, SCAN_B, 0, stream>>>(offs, bsum, cursor, N_NODES, N_EDGES);
    place_edges<<<(N_EDGES + 255) / 256, 256, 0, stream>>>(e_src, e_dst, edge_labels, cursor,
                                                           src_s, lab_s);

    // weight prep
    dim3 pb(16, 16);
    wprep<<<dim3(32, 8, N_LAYERS), pb, 0, stream>>>(mlp_W1, W1t_h, W1t_l, 128, 512, 512,
                                                    (long)384 * 256, (long)512 * 128, 1);
    wprep<<<dim3(8, 16, N_LAYERS), pb, 0, stream>>>(mlp_W2, W2t_h, W2t_l, 256, 128, 128,
                                                    (long)256 * 128, (long)128 * 256, 0);
    wprep<<<dim3(8, 4, 1), pb, 0, stream>>>(enc_W0, e0h, e0l, 64, 128, 128, 0, 0, 0);
    wprep<<<dim3(8, 8, 1), pb, 0, stream>>>(enc_W1, e1h, e1l, 128, 128, 128, 0, 0, 0);
    wprep<<<dim3(8, 8, 1), pb, 0, stream>>>(dec_W0, d0h, d0l, 128, 128, 128, 0, 0, 0);
    wprep<<<dim3(8, 8, 1), pb, 0, stream>>>(dec_Wl, dlh, dll, 128, 100, 128, 0, 0, 0);

    // all-layer etype projections, one dispatch (stores SCL-scaled)
    etype_proj_all<<<dim3(N_ETYPES, N_LAYERS), 256, 0, stream>>>(edge_emb, mlp_W1, mlp_b1, etp_all);

    dim3 blk(256);
    const int MT_N = (N_NODES + 63) / 64;           // 782
    const int MT_V = (N_VARS + 63) / 64;            // 313
    const int PER_N = (MT_N + 7) / 8;               // 98 m-panels per XCD
    const int PER_V = (MT_V + 7) / 8;               // 40

    // encoder: enc0 fp32-A keeps LDS path; enc1 ASPLIT -> LDS-free register path
    gemm3h<EPI_BIAS_RELU, 0, 1, 1, 2><<<dim3(8, PER_N * 2), blk, 0, stream>>>(
        node_labels, nullptr, nullptr, e0h, e0l, enc_b0, nullptr,
        nullptr, hench, hencl, N_NODES, 128, 64, 128);
    gemm3r<EPI_BIAS, 1, 1, 2><<<dim3(8, PER_N * 2), blk, 0, stream>>>(
        hench, hencl, e1h, e1l, enc_b1, nullptr,
        nullptr, hhi, hlo, N_NODES, 128, 128, 128);

    // message-passing layers: LDS-free register GEMMs (R10)
    for (int l = 0; l < N_LAYERS; ++l) {
        const float* b2 = mlp_b2 + (size_t)l * DMODEL;
        gemm3r<EPI_NONE, 3, 1, 8><<<dim3(8, PER_N * 8), blk, 0, stream>>>(
            hhi, hlo, W1t_h + (size_t)l * 512 * 128, W1t_l + (size_t)l * 512 * 128,
            nullptr, nullptr, HHd, HHs, nullptr, N_NODES, 512, 128, 256);
        edge_agg<<<(N_NODES + 3) / 4, blk, 0, stream>>>(
            HHd, HHs, etp_all + (size_t)l * N_ETYPES * 256, offs, src_s, lab_s, Phi, Plo);
        gemm3r<EPI_DEG_GELU, 1, 1, 2><<<dim3(8, PER_N * 2), blk, 0, stream>>>(
            Phi, Plo, W2t_h + (size_t)l * 128 * 256, W2t_l + (size_t)l * 128 * 256,
            b2, deg, nullptr, hhi, hlo, N_NODES, 128, 256, 128);
    }

    // readout: scatter-mean into variables
    readout_scatter<<<(N_MENTIONS + 1) / 2, 256, 0, stream>>>(hhi, hlo, var_gather, var_scatter,
                                                              vsum, vcnt);
    divide_kernel<<<N_VARS, DMODEL, 0, stream>>>(vsum, vcnt);

    // decoder: dec0 fp32-A keeps LDS path; dec-final ASPLIT -> LDS-free register path
    gemm3h<EPI_BIAS_RELU, 0, 1, 1, 2><<<dim3(8, PER_V * 2), blk, 0, stream>>>(
        vsum, nullptr, nullptr, d0h, d0l, dec_b0, nullptr,
        nullptr, dtmph, dtmpl, N_VARS, 128, 128, 128);
    gemm3r<EPI_BIAS, 0, 1, 2><<<dim3(8, PER_V * 2), blk, 0, stream>>>(
        dtmph, dtmpl, dlh, dll, dec_bl, nullptr,
        out, nullptr, nullptr, N_VARS, OUT_DIM, 128, OUT_DIM);
}

// Round 11
// 1265.401 us; speedup vs baseline: 1.6055x; 1.6055x over previous
//
#include <hip/hip_runtime.h>
#include <math.h>

#define N_NODES 50000
#define N_EDGES 600000
#define IN_DIM 64
#define DMODEL 128
#define N_LAYERS 8
#define N_ETYPES 44
#define N_MENTIONS 100000
#define N_VARS 20000
#define OUT_DIM 100

#define EPI_BIAS 0
#define EPI_BIAS_RELU 1
#define EPI_DEG_GELU 2
#define EPI_NONE 3

#define SCL  6.103515625e-05f   /* 2^-14: pre-scale into f16 range (|h| can reach ~1e7) */
#define SCLI 16384.0f

typedef _Float16 f16x8 __attribute__((ext_vector_type(8)));
typedef _Float16 f16x4 __attribute__((ext_vector_type(4)));
typedef float f32x4 __attribute__((ext_vector_type(4)));

// global->LDS DMA, 16B/lane: dest = wave-uniform base + lane*16 (rule: no per-lane scatter)
#define GLOAD_LDS16(g, l) __builtin_amdgcn_global_load_lds( \
    (const __attribute__((address_space(1))) void*)(g),      \
    (__attribute__((address_space(3))) void*)(l), 16, 0, 0)

__device__ __forceinline__ float gelu_exact(float x) {
    return 0.5f * x * (1.0f + erff(x * 0.70710678118654752f));
}

// ---------------- weight prep: transpose [K,N]->[Npad,K] and split fp32 -> f16 hi+lo ----------
__global__ void wprep(const float* __restrict__ src, _Float16* __restrict__ dhi,
                      _Float16* __restrict__ dlo, int K, int Nsrc, int Npad,
                      long srcLS, long dstLS, int cat) {
    __shared__ float sh[16][17];
    int z = blockIdx.z;
    src += (size_t)z * srcLS;
    dhi += (size_t)z * dstLS;
    dlo += (size_t)z * dstLS;
    int n0 = blockIdx.x * 16, k0 = blockIdx.y * 16;
    int tx = threadIdx.x, ty = threadIdx.y;
    int nr = n0 + tx, kr = k0 + ty;
    float v;
    if (cat) {
        int half = nr >> 8;
        int nc = nr & 255;
        v = src[(size_t)(kr + half * 128) * 256 + nc];
    } else {
        v = (nr < Nsrc) ? src[(size_t)kr * Nsrc + nr] : 0.f;
    }
    sh[ty][tx] = v;
    __syncthreads();
    float x = sh[tx][ty];
    int n = n0 + ty, k = k0 + tx;
    _Float16 hi = (_Float16)x;
    float lo = x - (float)hi;
    dhi[(size_t)n * K + k] = hi;
    dlo[(size_t)n * K + k] = (_Float16)lo;
}

// ---------------- 3xF16 MFMA GEMM, 64x64 tile, reg-staged LDS (ASPLIT=0 paths) ----------------
// MSWZ=1: XCD-aware grid remap for A-panel L2 reuse (R3: -117us; R5: generalized NX).
// R4: fusing BW-pinned gather with MFMA dropped gather occupancy 68%->18%.
// R7/R8: 128^2 and 64x128 tiles regressed (short-K wants occupancy).
// R10: LDS-free fragment-from-global regressed 57->101us (serial L2-latency chain per wave;
//      MfmaUtil 7.5%, both pipes idle) -> LDS staging is what decouples the latency chain.
template<int EPI, int ASPLIT, int OSPLIT, int MSWZ = 0, int NX = 8>
__global__ __launch_bounds__(256) void gemm3h(
        const float* __restrict__ A, const _Float16* __restrict__ Ahi,
        const _Float16* __restrict__ Alo,
        const _Float16* __restrict__ Bh, const _Float16* __restrict__ Bl,
        const float* __restrict__ bias, const int* __restrict__ deg,
        float* __restrict__ C, _Float16* __restrict__ Chi, _Float16* __restrict__ Clo,
        int M, int N, int K, int ldC) {
    __shared__ _Float16 Ah[64 * 56], Al[64 * 56], Bsh[64 * 56], Bsl[64 * 56];
    int t = threadIdx.x;
    int m0, n0;
    if (MSWZ) {
        int mpanels = (M + 63) >> 6;
        int per = (mpanels + 7) >> 3;                     // m-panels per XCD
        int mi = blockIdx.x * per + blockIdx.y / NX;
        if (mi >= mpanels) return;                        // uniform early-out, pre-barrier
        m0 = mi * 64;
        n0 = (blockIdx.y % NX) * 64;
    } else {
        m0 = blockIdx.y * 64;
        n0 = blockIdx.x * 64;
    }
    int ar = t >> 2, ac = (t & 3) * 8;
    int btt = t & 127, br = btt >> 1, bc = (btt & 1) * 16;
    const _Float16* Bsrc = (t < 128) ? Bh : Bl;
    _Float16* Bdst = (t < 128) ? Bsh : Bsl;
    int lane = t & 63, wid = t >> 6;
    int wm = (wid >> 1) * 32, wn = (wid & 1) * 32;
    int quad = lane >> 4, l15 = lane & 15;
    f32x4 acc[2][2] = {};
    bool arow_ok = (m0 + ar) < M;
    const float* Aptr = ASPLIT ? nullptr : (A + (size_t)(m0 + ar) * K + ac);
    const _Float16* Ahp = ASPLIT ? (Ahi + (size_t)(m0 + ar) * K + ac) : nullptr;
    const _Float16* Alp = ASPLIT ? (Alo + (size_t)(m0 + ar) * K + ac) : nullptr;
    const _Float16* Bptr = Bsrc + (size_t)(n0 + br) * K + bc;

    for (int k0 = 0; k0 < K; k0 += 32) {
        f16x8 hv = {}, lv = {};
        if (ASPLIT) {
            if (arow_ok) {
                hv = *(const f16x8*)(Ahp + k0);
                lv = *(const f16x8*)(Alp + k0);
            }
        } else {
            float4 v0 = {0, 0, 0, 0}, v1 = {0, 0, 0, 0};
            if (arow_ok) {
                v0 = *(const float4*)(Aptr + k0);
                v1 = *(const float4*)(Aptr + k0 + 4);
            }
            float xs[8] = {v0.x, v0.y, v0.z, v0.w, v1.x, v1.y, v1.z, v1.w};
#pragma unroll
            for (int j = 0; j < 8; j++) {
                float s = xs[j] * SCL;
                _Float16 h = (_Float16)s;
                hv[j] = h;
                lv[j] = (_Float16)(s - (float)h);
            }
        }
        *(f16x8*)&Ah[ar * 56 + ac] = hv;
        *(f16x8*)&Al[ar * 56 + ac] = lv;
        f16x8 b0 = *(const f16x8*)(Bptr + k0);
        f16x8 b1v = *(const f16x8*)(Bptr + k0 + 8);
        *(f16x8*)&Bdst[br * 56 + bc] = b0;
        *(f16x8*)&Bdst[br * 56 + bc + 8] = b1v;
        __syncthreads();

        f16x8 afh[2], afl[2], bfh[2], bfl[2];
#pragma unroll
        for (int i = 0; i < 2; i++) {
            int am = (wm + i * 16 + l15) * 56 + quad * 8;
            afh[i] = *(const f16x8*)&Ah[am];
            afl[i] = *(const f16x8*)&Al[am];
            int bn = (wn + i * 16 + l15) * 56 + quad * 8;
            bfh[i] = *(const f16x8*)&Bsh[bn];
            bfl[i] = *(const f16x8*)&Bsl[bn];
        }
#pragma unroll
        for (int i = 0; i < 2; i++)
#pragma unroll
            for (int j = 0; j < 2; j++) {
                acc[i][j] = __builtin_amdgcn_mfma_f32_16x16x32_f16(afh[i], bfh[j], acc[i][j], 0, 0, 0);
                acc[i][j] = __builtin_amdgcn_mfma_f32_16x16x32_f16(afh[i], bfl[j], acc[i][j], 0, 0, 0);
                acc[i][j] = __builtin_amdgcn_mfma_f32_16x16x32_f16(afl[i], bfh[j], acc[i][j], 0, 0, 0);
            }
        __syncthreads();
    }

#pragma unroll
    for (int i = 0; i < 2; i++) {
        int rowb = m0 + wm + i * 16 + quad * 4;
#pragma unroll
        for (int j = 0; j < 2; j++) {
            int col = n0 + wn + j * 16 + l15;
            if (col >= N) continue;
#pragma unroll
            for (int r = 0; r < 4; r++) {
                int row = rowb + r;
                if (row >= M) continue;
                float v = acc[i][j][r] * SCLI;
                if (EPI == EPI_BIAS) { v += bias[col]; }
                else if (EPI == EPI_BIAS_RELU) { v += bias[col]; v = fmaxf(v, 0.f); }
                else if (EPI == EPI_DEG_GELU) { v += (float)deg[row] * bias[col]; v = gelu_exact(v); }
                if (OSPLIT == 0) {
                    C[(size_t)row * ldC + col] = v;
                } else if (OSPLIT == 1) {
                    float s = v * SCL;
                    _Float16 h = (_Float16)s;
                    size_t idx = (size_t)row * ldC + col;
                    Chi[idx] = h;
                    Clo[idx] = (_Float16)(s - (float)h);
                } else if (OSPLIT == 3) {
                    if (col < 256) C[(size_t)row * 256 + col] = v;
                    else Chi[(size_t)row * 256 + (col - 256)] = (_Float16)(v * SCL);
                }
            }
        }
    }
}

// ---------------- 3xF16 MFMA GEMM, 64x64 tile, global_load_lds staging (R11, ASPLIT paths) ----
// Common-mistake #1 fix: gemm3h reg-stages (4 global loads -> VGPR -> 4 ds_writes + addr
// VALU per K-step). Here each wave issues 4 global_load_lds (16B/lane = 1KB each), staging
// its OWN buffer (wave 0->Ah, 1->Al, 2->Bh, 3->Bl; 64 rows x 32 halves, linear 64B rows).
// No VGPR round-trip, no ds_writes. LDS 28->16KB -> ~7-8 blocks/CU (was 5).
// Bank fix (rule #21, both-sides involution): linear 64B rows give 8-way read conflicts;
// stage source slot ss = sd ^ (row&3) and read at slot quad ^ (row&3) -> 4-way (1.58x).
// Data lands bit-identically; same MFMA sequence as gemm3h -> bit-identical output.
template<int EPI, int OSPLIT, int NX>
__global__ __launch_bounds__(256) void gemm3g(
        const _Float16* __restrict__ Ahi, const _Float16* __restrict__ Alo,
        const _Float16* __restrict__ Bh, const _Float16* __restrict__ Bl,
        const float* __restrict__ bias, const int* __restrict__ deg,
        float* __restrict__ C, _Float16* __restrict__ Chi, _Float16* __restrict__ Clo,
        int M, int N, int K, int ldC) {
    __shared__ _Float16 Ah[64 * 32], Al[64 * 32], Bsh[64 * 32], Bsl[64 * 32];
    int t = threadIdx.x;
    int mpanels = (M + 63) >> 6;
    int per = (mpanels + 7) >> 3;
    int mi = blockIdx.x * per + blockIdx.y / NX;
    if (mi >= mpanels) return;                 // uniform early-out, pre-barrier
    int m0 = mi * 64;
    int n0 = (blockIdx.y % NX) * 64;
    int lane = t & 63, wid = t >> 6;
    int wm = (wid >> 1) * 32, wn = (wid & 1) * 32;
    int quad = lane >> 4, l15 = lane & 15;
    f32x4 acc[2][2] = {};

    // staging setup: wave wid owns one buffer; lane covers dest row r=16s+(lane>>2),
    // dest slot sd=lane&3 (16B slots); source slot ss = sd ^ (r&3) (involution swizzle)
    _Float16* dst = (wid == 0) ? Ah : (wid == 1) ? Al : (wid == 2) ? Bsh : Bsl;
    const _Float16* gbase = (wid == 0) ? Ahi : (wid == 1) ? Alo : (wid == 2) ? Bh : Bl;
    int base_row = (wid < 2) ? m0 : n0;
    int r_l = lane >> 2;                       // 0..15 within stripe
    int ss = (lane & 3) ^ (r_l & 3);           // row&3 == r_l&3 (stripe base is mult of 16)
    const _Float16* gp[4];
#pragma unroll
    for (int s = 0; s < 4; ++s) {
        int grow = base_row + 16 * s + r_l;
        if (wid < 2 && grow > M - 1) grow = M - 1;   // A-tail clamp (dup row, dead acc)
        gp[s] = gbase + (size_t)grow * K + ss * 8;   // B rows always valid (wprep pads)
    }

    for (int k0 = 0; k0 < K; k0 += 32) {
#pragma unroll
        for (int s = 0; s < 4; ++s)
            GLOAD_LDS16(gp[s] + k0, dst + s * 512);  // 1KB per issue; lane*16B auto-offset
        __syncthreads();                             // drains vmcnt before reads

        f16x8 afh[2], afl[2], bfh[2], bfl[2];
#pragma unroll
        for (int i = 0; i < 2; i++) {
            int arow = wm + i * 16 + l15;
            int ao = arow * 32 + ((quad ^ (arow & 3)) * 8);
            afh[i] = *(const f16x8*)&Ah[ao];
            afl[i] = *(const f16x8*)&Al[ao];
            int brow = wn + i * 16 + l15;
            int bo = brow * 32 + ((quad ^ (brow & 3)) * 8);
            bfh[i] = *(const f16x8*)&Bsh[bo];
            bfl[i] = *(const f16x8*)&Bsl[bo];
        }
#pragma unroll
        for (int i = 0; i < 2; i++)
#pragma unroll
            for (int j = 0; j < 2; j++) {
                acc[i][j] = __builtin_amdgcn_mfma_f32_16x16x32_f16(afh[i], bfh[j], acc[i][j], 0, 0, 0);
                acc[i][j] = __builtin_amdgcn_mfma_f32_16x16x32_f16(afh[i], bfl[j], acc[i][j], 0, 0, 0);
                acc[i][j] = __builtin_amdgcn_mfma_f32_16x16x32_f16(afl[i], bfh[j], acc[i][j], 0, 0, 0);
            }
        __syncthreads();                             // reads done before next stage
    }

#pragma unroll
    for (int i = 0; i < 2; i++) {
        int rowb = m0 + wm + i * 16 + quad * 4;
#pragma unroll
        for (int j = 0; j < 2; j++) {
            int col = n0 + wn + j * 16 + l15;
            if (col >= N) continue;
#pragma unroll
            for (int r = 0; r < 4; r++) {
                int row = rowb + r;
                if (row >= M) continue;
                float v = acc[i][j][r] * SCLI;
                if (EPI == EPI_BIAS) { v += bias[col]; }
                else if (EPI == EPI_BIAS_RELU) { v += bias[col]; v = fmaxf(v, 0.f); }
                else if (EPI == EPI_DEG_GELU) { v += (float)deg[row] * bias[col]; v = gelu_exact(v); }
                if (OSPLIT == 0) {
                    C[(size_t)row * ldC + col] = v;
                } else if (OSPLIT == 1) {
                    float s = v * SCL;
                    _Float16 h = (_Float16)s;
                    size_t idx = (size_t)row * ldC + col;
                    Chi[idx] = h;
                    Clo[idx] = (_Float16)(s - (float)h);
                } else if (OSPLIT == 3) {
                    // mixed W1 output: Hd fp32 / Hs single f16 (SCL-scaled)
                    if (col < 256) C[(size_t)row * 256 + col] = v;
                    else Chi[(size_t)row * 256 + (col - 256)] = (_Float16)(v * SCL);
                }
            }
        }
    }
}

// ---------------- CSR build ----------------
__global__ void count_deg(const int* __restrict__ dst, int* __restrict__ deg) {
    int e = blockIdx.x * blockDim.x + threadIdx.x;
    if (e < N_EDGES) atomicAdd(&deg[dst[e]], 1);
}

#define SCAN_B 1024
#define SCAN_NB ((N_NODES + SCAN_B - 1) / SCAN_B)

__global__ void scan_local(const int* __restrict__ deg, int* __restrict__ offs,
                           int* __restrict__ bsum, int n) {
    __shared__ int sh[SCAN_B];
    int t = threadIdx.x;
    int i = blockIdx.x * SCAN_B + t;
    int v = (i < n) ? deg[i] : 0;
    sh[t] = v;
    __syncthreads();
    for (int o = 1; o < SCAN_B; o <<= 1) {
        int u = (t >= o) ? sh[t - o] : 0;
        __syncthreads();
        sh[t] += u;
        __syncthreads();
    }
    if (i < n) offs[i] = sh[t] - v;
    if (t == SCAN_B - 1) bsum[blockIdx.x] = sh[t];
}

__global__ void scan_block(int* __restrict__ bsum, int nb) {
    __shared__ int sh[64];
    int t = threadIdx.x;
    int v = (t < nb) ? bsum[t] : 0;
    sh[t] = v;
    __syncthreads();
    for (int o = 1; o < 64; o <<= 1) {
        int u = (t >= o) ? sh[t - o] : 0;
        __syncthreads();
        sh[t] += u;
        __syncthreads();
    }
    if (t < nb) bsum[t] = sh[t] - v;
}

__global__ void scan_final(int* __restrict__ offs, const int* __restrict__ bsum,
                           int* __restrict__ cursor, int n, int total) {
    int i = blockIdx.x * SCAN_B + threadIdx.x;
    if (i < n) {
        int o = offs[i] + bsum[blockIdx.x];
        offs[i] = o;
        cursor[i] = o;
    }
    if (i == n) offs[n] = total;
}

__global__ void place_edges(const int* __restrict__ src, const int* __restrict__ dst,
                            const int* __restrict__ lab, int* __restrict__ cursor,
                            int* __restrict__ src_s, int* __restrict__ lab_s) {
    int e = blockIdx.x * blockDim.x + threadIdx.x;
    if (e < N_EDGES) {
        int pos = atomicAdd(&cursor[dst[e]], 1);
        src_s[pos] = src[e];
        lab_s[pos] = lab[e];
    }
}

// ---------------- per-etype projection, all layers in one dispatch ----------------
// Stores etp pre-scaled by SCL (R6): edge_agg's relu-sum runs in the scaled domain.
__global__ void etype_proj_all(const float* __restrict__ edge_emb, const float* __restrict__ mlp_W1,
                               const float* __restrict__ mlp_b1, float* __restrict__ etp_all) {
    int et = blockIdx.x;   // 0..43
    int l  = blockIdx.y;   // 0..7
    int c = threadIdx.x;   // 256
    const float* ee = edge_emb + (size_t)l * N_ETYPES * DMODEL + (size_t)et * DMODEL;
    const float* W  = mlp_W1 + (size_t)l * 384 * 256 + (size_t)256 * 256;
    float s = mlp_b1[(size_t)l * 256 + c];
    for (int k = 0; k < DMODEL; k++)
        s += ee[k] * W[(size_t)k * 256 + c];
    etp_all[((size_t)l * N_ETYPES + et) * 256 + c] = s * SCL;
}

// ---------------- edge aggregation: wave-per-node, 2-deep software pipeline (R9) ----------------
// R6: Hs gathered as single f16 (512B/row); Hd fp32 (coherent-error side); SCL-scaled domain.
// R9: 2-deep prefetch pipeline (+1.5us only — compiler already scheduled well; kept, free).
// R2/R4: BW-pinned above ~68% occupancy; keep lean. launch_bounds(256,8) pins VGPR <= 64.
__global__ __launch_bounds__(256, 8) void edge_agg(
        const float* __restrict__ HHd, const _Float16* __restrict__ HHs,
        const float* __restrict__ etp,
        const int* __restrict__ offsets, const int* __restrict__ src_s,
        const int* __restrict__ lab_s, _Float16* __restrict__ Phi,
        _Float16* __restrict__ Plo) {
    int wid = threadIdx.x >> 6, tl = threadIdx.x & 63;
    int i = blockIdx.x * 4 + wid;
    if (i >= N_NODES) return;
    int c4 = tl * 4;
    float4 hd = *(const float4*)&HHd[(size_t)i * 256 + c4];
    float hdx = hd.x * SCL, hdy = hd.y * SCL, hdz = hd.z * SCL, hdw = hd.w * SCL;
    float4 acc = {0.f, 0.f, 0.f, 0.f};
    int e0 = offsets[i], e1 = offsets[i + 1];
    int e = e0;
    int ng = (e1 - e0) >> 2;
    if (ng > 0) {
        int s0 = src_s[e0],     s1 = src_s[e0 + 1], s2 = src_s[e0 + 2], s3 = src_s[e0 + 3];
        int l0 = lab_s[e0],     l1 = lab_s[e0 + 1], l2 = lab_s[e0 + 2], l3 = lab_s[e0 + 3];
        f16x4 hs0 = *(const f16x4*)&HHs[(size_t)s0 * 256 + c4];
        f16x4 hs1 = *(const f16x4*)&HHs[(size_t)s1 * 256 + c4];
        f16x4 hs2 = *(const f16x4*)&HHs[(size_t)s2 * 256 + c4];
        f16x4 hs3 = *(const f16x4*)&HHs[(size_t)s3 * 256 + c4];
        for (int g = 0; g < ng; ++g) {
            int en = e0 + g * 4 + 4;
            if (en > e1 - 4) en = e1 - 4;
            int t0 = src_s[en],     t1 = src_s[en + 1], t2 = src_s[en + 2], t3 = src_s[en + 3];
            int m0 = lab_s[en],     m1 = lab_s[en + 1], m2 = lab_s[en + 2], m3 = lab_s[en + 3];
            f16x4 nh0 = *(const f16x4*)&HHs[(size_t)t0 * 256 + c4];
            f16x4 nh1 = *(const f16x4*)&HHs[(size_t)t1 * 256 + c4];
            f16x4 nh2 = *(const f16x4*)&HHs[(size_t)t2 * 256 + c4];
            f16x4 nh3 = *(const f16x4*)&HHs[(size_t)t3 * 256 + c4];
            float4 et0 = *(const float4*)&etp[l0 * 256 + c4];
            float4 et1 = *(const float4*)&etp[l1 * 256 + c4];
            float4 et2 = *(const float4*)&etp[l2 * 256 + c4];
            float4 et3 = *(const float4*)&etp[l3 * 256 + c4];
            acc.x += fmaxf(hdx + (float)hs0[0] + et0.x, 0.f) + fmaxf(hdx + (float)hs1[0] + et1.x, 0.f)
                   + fmaxf(hdx + (float)hs2[0] + et2.x, 0.f) + fmaxf(hdx + (float)hs3[0] + et3.x, 0.f);
            acc.y += fmaxf(hdy + (float)hs0[1] + et0.y, 0.f) + fmaxf(hdy + (float)hs1[1] + et1.y, 0.f)
                   + fmaxf(hdy + (float)hs2[1] + et2.y, 0.f) + fmaxf(hdy + (float)hs3[1] + et3.y, 0.f);
            acc.z += fmaxf(hdz + (float)hs0[2] + et0.z, 0.f) + fmaxf(hdz + (float)hs1[2] + et1.z, 0.f)
                   + fmaxf(hdz + (float)hs2[2] + et2.z, 0.f) + fmaxf(hdz + (float)hs3[2] + et3.z, 0.f);
            acc.w += fmaxf(hdw + (float)hs0[3] + et0.w, 0.f) + fmaxf(hdw + (float)hs1[3] + et1.w, 0.f)
                   + fmaxf(hdw + (float)hs2[3] + et2.w, 0.f) + fmaxf(hdw + (float)hs3[3] + et3.w, 0.f);
            hs0 = nh0; hs1 = nh1; hs2 = nh2; hs3 = nh3;
            l0 = m0; l1 = m1; l2 = m2; l3 = m3;
        }
        e = e0 + ng * 4;
    }
    for (; e < e1; ++e) {
        int s0 = src_s[e], l0 = lab_s[e];
        f16x4 hs0 = *(const f16x4*)&HHs[(size_t)s0 * 256 + c4];
        float4 et0 = *(const float4*)&etp[l0 * 256 + c4];
        acc.x += fmaxf(hdx + (float)hs0[0] + et0.x, 0.f);
        acc.y += fmaxf(hdy + (float)hs0[1] + et0.y, 0.f);
        acc.z += fmaxf(hdz + (float)hs0[2] + et0.z, 0.f);
        acc.w += fmaxf(hdw + (float)hs0[3] + et0.w, 0.f);
    }
    float sv[4] = {acc.x, acc.y, acc.z, acc.w};
    f16x4 ph, pl;
#pragma unroll
    for (int j = 0; j < 4; j++) {
        _Float16 h = (_Float16)sv[j];
        ph[j] = h;
        pl[j] = (_Float16)(sv[j] - (float)h);
    }
    *(f16x4*)&Phi[(size_t)i * 256 + c4] = ph;
    *(f16x4*)&Plo[(size_t)i * 256 + c4] = pl;
}

// ---------------- readout ----------------
__global__ void readout_scatter(const _Float16* __restrict__ hhi, const _Float16* __restrict__ hlo,
                                const int* __restrict__ vg, const int* __restrict__ vs,
                                float* __restrict__ sums, int* __restrict__ cnt) {
    int m = blockIdx.x * 2 + (threadIdx.x >> 7);
    int c = threadIdx.x & 127;
    if (m >= N_MENTIONS) return;
    int node = vg[m];
    int v = vs[m];
    size_t idx = (size_t)node * DMODEL + c;
    float x = ((float)hhi[idx] + (float)hlo[idx]) * SCLI;
    atomicAdd(&sums[(size_t)v * DMODEL + c], x);
    if (c == 0) atomicAdd(&cnt[v], 1);
}

__global__ void divide_kernel(float* __restrict__ sums, const int* __restrict__ cnt) {
    int v = blockIdx.x;
    int c = threadIdx.x;  // 128
    float d = (float)max(cnt[v], 1);
    sums[(size_t)v * DMODEL + c] /= d;
}

// ---------------- launcher ----------------
extern "C" void kernel_launch(void* const* d_in, const int* in_sizes, int n_in,
                              void* d_out, int out_size, void* d_ws, size_t ws_size,
                              hipStream_t stream) {
    const float* node_labels = (const float*)d_in[0];
    const int*   edges       = (const int*)d_in[1];
    const int*   edge_labels = (const int*)d_in[2];
    const int*   var_gather  = (const int*)d_in[3];
    const int*   var_scatter = (const int*)d_in[4];
    const float* enc_W0 = (const float*)d_in[7];
    const float* enc_b0 = (const float*)d_in[8];
    const float* enc_W1 = (const float*)d_in[9];
    const float* enc_b1 = (const float*)d_in[10];
    const float* edge_emb = (const float*)d_in[11];
    const float* mlp_W1 = (const float*)d_in[12];
    const float* mlp_b1 = (const float*)d_in[13];
    const float* mlp_W2 = (const float*)d_in[14];
    const float* mlp_b2 = (const float*)d_in[15];
    const float* dec_W0 = (const float*)d_in[16];
    const float* dec_b0 = (const float*)d_in[17];
    const float* dec_Wl = (const float*)d_in[18];
    const float* dec_bl = (const float*)d_in[19];
    float* out = (float*)d_out;

    char* ws = (char*)d_ws;
    size_t off = 0;
    auto alloc = [&](size_t bytes) -> void* {
        void* p = ws + off;
        off += (bytes + 255) & ~(size_t)255;
        return p;
    };
    float*    HHd   = (float*)alloc((size_t)N_NODES * 256 * 4);       // 51.2 MB (Hd, fp32)
    _Float16* HHs   = (_Float16*)alloc((size_t)N_NODES * 256 * 2);    // 25.6 MB (Hs, f16)
    _Float16* hhi   = (_Float16*)alloc((size_t)N_NODES * DMODEL * 2);
    _Float16* hlo   = (_Float16*)alloc((size_t)N_NODES * DMODEL * 2);
    _Float16* Phi   = (_Float16*)alloc((size_t)N_NODES * 256 * 2);
    _Float16* Plo   = (_Float16*)alloc((size_t)N_NODES * 256 * 2);
    float* etp_all = (float*)alloc((size_t)N_LAYERS * N_ETYPES * 256 * 4);
    int* deg    = (int*)alloc((size_t)N_NODES * 4);
    int* offs   = (int*)alloc((size_t)(N_NODES + 1) * 4);
    int* cursor = (int*)alloc((size_t)N_NODES * 4);
    int* bsum   = (int*)alloc(64 * 4);
    int* src_s  = (int*)alloc((size_t)N_EDGES * 4);
    int* lab_s  = (int*)alloc((size_t)N_EDGES * 4);
    _Float16* W1t_h = (_Float16*)alloc((size_t)N_LAYERS * 512 * 128 * 2);
    _Float16* W1t_l = (_Float16*)alloc((size_t)N_LAYERS * 512 * 128 * 2);
    _Float16* W2t_h = (_Float16*)alloc((size_t)N_LAYERS * 128 * 256 * 2);
    _Float16* W2t_l = (_Float16*)alloc((size_t)N_LAYERS * 128 * 256 * 2);
    _Float16* e0h = (_Float16*)alloc(128 * 64 * 2);
    _Float16* e0l = (_Float16*)alloc(128 * 64 * 2);
    _Float16* e1h = (_Float16*)alloc(128 * 128 * 2);
    _Float16* e1l = (_Float16*)alloc(128 * 128 * 2);
    _Float16* d0h = (_Float16*)alloc(128 * 128 * 2);
    _Float16* d0l = (_Float16*)alloc(128 * 128 * 2);
    _Float16* dlh = (_Float16*)alloc(128 * 128 * 2);
    _Float16* dll = (_Float16*)alloc(128 * 128 * 2);
    _Float16* hench = (_Float16*)alloc((size_t)N_NODES * DMODEL * 2);
    _Float16* hencl = (_Float16*)alloc((size_t)N_NODES * DMODEL * 2);
    float* vsum = (float*)alloc((size_t)N_VARS * DMODEL * 4);
    int*   vcnt = (int*)alloc((size_t)N_VARS * 4);
    _Float16* dtmph = (_Float16*)alloc((size_t)N_VARS * DMODEL * 2);
    _Float16* dtmpl = (_Float16*)alloc((size_t)N_VARS * DMODEL * 2);

    const int* e_src = edges;
    const int* e_dst = edges + N_EDGES;

    hipMemsetAsync(deg, 0, (size_t)N_NODES * 4, stream);
    hipMemsetAsync(vsum, 0, (size_t)N_VARS * DMODEL * 4, stream);
    hipMemsetAsync(vcnt, 0, (size_t)N_VARS * 4, stream);

    // CSR build (hierarchical scan)
    count_deg<<<(N_EDGES + 255) / 256, 256, 0, stream>>>(e_dst, deg);
    scan_local<<<SCAN_NB, SCAN_B, 0, stream>>>(deg, offs, bsum, N_NODES);
    scan_block<<<1, 64, 0, stream>>>(bsum, SCAN_NB);
    scan_final<<<SCAN_NB, SCAN_B, 0, stream>>>(offs, bsum, cursor, N_NODES, N_EDGES);
    place_edges<<<(N_EDGES + 255) / 256, 256, 0, stream>>>(e_src, e_dst, edge_labels, cursor,
                                                           src_s, lab_s);

    // weight prep
    dim3 pb(16, 16);
    wprep<<<dim3(32, 8, N_LAYERS), pb, 0, stream>>>(mlp_W1, W1t_h, W1t_l, 128, 512, 512,
                                                    (long)384 * 256, (long)512 * 128, 1);
    wprep<<<dim3(8, 16, N_LAYERS), pb, 0, stream>>>(mlp_W2, W2t_h, W2t_l, 256, 128, 128,
                                                    (long)256 * 128, (long)128 * 256, 0);
    wprep<<<dim3(8, 4, 1), pb, 0, stream>>>(enc_W0, e0h, e0l, 64, 128, 128, 0, 0, 0);
    wprep<<<dim3(8, 8, 1), pb, 0, stream>>>(enc_W1, e1h, e1l, 128, 128, 128, 0, 0, 0);
    wprep<<<dim3(8, 8, 1), pb, 0, stream>>>(dec_W0, d0h, d0l, 128, 128, 128, 0, 0, 0);
    wprep<<<dim3(8, 8, 1), pb, 0, stream>>>(dec_Wl, dlh, dll, 128, 100, 128, 0, 0, 0);

    // all-layer etype projections, one dispatch (stores SCL-scaled)
    etype_proj_all<<<dim3(N_ETYPES, N_LAYERS), 256, 0, stream>>>(edge_emb, mlp_W1, mlp_b1, etp_all);

    dim3 blk(256);
    const int MT_N = (N_NODES + 63) / 64;           // 782
    const int MT_V = (N_VARS + 63) / 64;            // 313
    const int PER_N = (MT_N + 7) / 8;               // 98 m-panels per XCD
    const int PER_V = (MT_V + 7) / 8;               // 40

    // encoder: enc0 fp32-A keeps reg-staged path; enc1 ASPLIT -> global_load_lds path
    gemm3h<EPI_BIAS_RELU, 0, 1, 1, 2><<<dim3(8, PER_N * 2), blk, 0, stream>>>(
        node_labels, nullptr, nullptr, e0h, e0l, enc_b0, nullptr,
        nullptr, hench, hencl, N_NODES, 128, 64, 128);
    gemm3g<EPI_BIAS, 1, 2><<<dim3(8, PER_N * 2), blk, 0, stream>>>(
        hench, hencl, e1h, e1l, enc_b1, nullptr,
        nullptr, hhi, hlo, N_NODES, 128, 128, 128);

    // message-passing layers: global_load_lds GEMMs (R11)
    for (int l = 0; l < N_LAYERS; ++l) {
        const float* b2 = mlp_b2 + (size_t)l * DMODEL;
        gemm3g<EPI_NONE, 3, 8><<<dim3(8, PER_N * 8), blk, 0, stream>>>(
            hhi, hlo, W1t_h + (size_t)l * 512 * 128, W1t_l + (size_t)l * 512 * 128,
            nullptr, nullptr, HHd, HHs, nullptr, N_NODES, 512, 128, 256);
        edge_agg<<<(N_NODES + 3) / 4, blk, 0, stream>>>(
            HHd, HHs, etp_all + (size_t)l * N_ETYPES * 256, offs, src_s, lab_s, Phi, Plo);
        gemm3g<EPI_DEG_GELU, 1, 2><<<dim3(8, PER_N * 2), blk, 0, stream>>>(
            Phi, Plo, W2t_h + (size_t)l * 128 * 256, W2t_l + (size_t)l * 128 * 256,
            b2, deg, nullptr, hhi, hlo, N_NODES, 128, 256, 128);
    }

    // readout: scatter-mean into variables
    readout_scatter<<<(N_MENTIONS + 1) / 2, 256, 0, stream>>>(hhi, hlo, var_gather, var_scatter,
                                                              vsum, vcnt);
    divide_kernel<<<N_VARS, DMODEL, 0, stream>>>(vsum, vcnt);

    // decoder: dec0 fp32-A keeps reg-staged path; dec-final ASPLIT -> global_load_lds path
    gemm3h<EPI_BIAS_RELU, 0, 1, 1, 2><<<dim3(8, PER_V * 2), blk, 0, stream>>>(
        vsum, nullptr, nullptr, d0h, d0l, dec_b0, nullptr,
        nullptr, dtmph, dtmpl, N_VARS, 128, 128, 128);
    gemm3g<EPI_BIAS, 0, 2><<<dim3(8, PER_V * 2), blk, 0, stream>>>(
        dtmph, dtmpl, dlh, dll, dec_bl, nullptr,
        out, nullptr, nullptr, N_VARS, OUT_DIM, 128, OUT_DIM);
}